// Round 18
// baseline (288.688 us; speedup 1.0000x reference)
//
#include <hip/hip_runtime.h>
#include <hip/hip_bf16.h>

typedef unsigned short u16;
typedef __attribute__((ext_vector_type(8))) short short8;
typedef __attribute__((ext_vector_type(4))) float f32x4;
typedef unsigned long long u64;

#define DI __device__ __forceinline__

DI u16 f2b(float f){
  unsigned u = __float_as_uint(f);
  unsigned r = 0x7fffu + ((u >> 16) & 1u);
  return (u16)((u + r) >> 16);
}
DI float b2f(u16 u){ return __uint_as_float((unsigned)u << 16); }

DI void gl_lds16(const void* g, void* l){
  __builtin_amdgcn_global_load_lds((const __attribute__((address_space(1))) void*)g,
                                   (__attribute__((address_space(3))) void*)l, 16, 0, 0);
}

// ---------------- workspace layout (bytes) ----------------
constexpr size_t O_XBF = 0;
constexpr size_t O_W0T = O_XBF + 33554432;
constexpr size_t O_WGT = O_W0T + 8388608;
constexpr size_t O_W2T = O_WGT + 4194304;
constexpr size_t O_XB  = O_W2T + 4194304;
constexpr size_t O_H   = O_XB  + 33554432;
constexpr size_t O_ES  = O_H   + 33554432;
constexpr size_t O_ED  = O_ES  + 524288;
constexpr size_t O_ADJ = O_ED  + 524288;
constexpr size_t O_SC0 = O_ADJ + 65536;
constexpr size_t O_SH0 = O_SC0 + 8192;
constexpr size_t O_SC2 = O_SH0 + 8192;
constexpr size_t O_SH2 = O_SC2 + 4096;
constexpr size_t O_LB0 = O_SH2 + 4096;
constexpr size_t O_LB1 = O_LB0 + 16384;
constexpr size_t O_Z1U = O_LB1 + 16384;        // 16384: step-0 uniform z1 f32[4096] (moved out of s2s overlay)
constexpr size_t S_AC0 = 0;
constexpr size_t S_AC1 = S_AC0 + 786432;
constexpr size_t S_C0  = S_AC1 + 524288;
constexpr size_t S_C1  = S_C0  + 524288;
constexpr size_t S_H1F = S_C1  + 524288;
constexpr size_t S_ZP  = S_H1F + 524288;
constexpr size_t S_E   = S_ZP  + 16777216;

// ---------------- one setup kernel: x cvt + transposes + prep + adjacency + s2s0 gemv ----------------
__global__ __launch_bounds__(256) void setup_all(
    const float* __restrict__ x,
    const float* __restrict__ W0, const float* __restrict__ Wg1,
    const float* __restrict__ Wg2, const float* __restrict__ W2,
    const float* __restrict__ g0, const float* __restrict__ b0, const float* __restrict__ m0, const float* __restrict__ v0,
    const float* __restrict__ g2, const float* __restrict__ b2, const float* __restrict__ m2, const float* __restrict__ v2,
    const float* __restrict__ bih0, const float* __restrict__ bhh0,
    const float* __restrict__ bih1, const float* __restrict__ bhh1,
    const float* __restrict__ pos, const float* __restrict__ Wih1,
    u16* __restrict__ xbf, u16* __restrict__ w0t, u16* __restrict__ wgt, u16* __restrict__ w2t,
    float* __restrict__ sc0, float* __restrict__ sh0, float* __restrict__ sc2, float* __restrict__ sh2,
    float* __restrict__ lb0, float* __restrict__ lb1, u64* __restrict__ adjm, float* __restrict__ z1u)
{
  __shared__ float tile[32][33];
  __shared__ float px[4][64], py[4][64];
  __shared__ float hs[1024];
  int bx = blockIdx.x, t = threadIdx.x;
  if(bx < 8192){
    int idx = bx * 256 + t;
    int r = idx >> 8, c8 = (idx & 255) << 3;
    const float* src = x + (size_t)r * 2048 + c8;
    float4 v0 = *(const float4*)src;
    float4 v1 = *(const float4*)(src + 4);
    short8 ov;
    ov[0] = (short)f2b(v0.x); ov[1] = (short)f2b(v0.y); ov[2] = (short)f2b(v0.z); ov[3] = (short)f2b(v0.w);
    ov[4] = (short)f2b(v1.x); ov[5] = (short)f2b(v1.y); ov[6] = (short)f2b(v1.z); ov[7] = (short)f2b(v1.w);
    *(short8*)(xbf + (size_t)r * 2048 + c8) = ov;
  } else if(bx < 16384){
    int bx2 = bx - 8192;
    int cx = bx2 & 127, by = bx2 >> 7;
    const float* src; u16* dst; int C, droff;
    if(cx < 64){      src = W0;  dst = w0t; C = 2048; droff = 0; }
    else if(cx < 80){ src = Wg1; dst = wgt; C = 512;  droff = 0;   cx -= 64; }
    else if(cx < 96){ src = Wg2; dst = wgt; C = 512;  droff = 512; cx -= 80; }
    else {            src = W2;  dst = w2t; C = 1024; droff = 0;   cx -= 96; }
    int c0 = cx * 32, r0 = by * 32;
    int tx = t & 31, ty = t >> 5;
    for(int i = 0; i < 4; i++)
      tile[ty + 8*i][tx] = src[(size_t)(r0 + ty + 8*i) * C + c0 + tx];
    __syncthreads();
    for(int i = 0; i < 4; i++)
      dst[(size_t)(droff + c0 + ty + 8*i) * 2048 + r0 + tx] = f2b(tile[tx][ty + 8*i]);
  } else if(bx < 16400){
    int tt = (bx - 16384) * 256 + t;
    if(tt < 2048){ float s = g0[tt] * rsqrtf(v0[tt] + 0.1f); sc0[tt] = s; sh0[tt] = b0[tt] - m0[tt] * s; }
    if(tt < 1024){ float s = g2[tt] * rsqrtf(v2[tt] + 0.1f); sc2[tt] = s; sh2[tt] = b2[tt] - m2[tt] * s; }
    lb0[tt] = bih0[tt] + bhh0[tt];
    lb1[tt] = bih1[tt] + bhh1[tt];
  } else if(bx < 16432){
    int w = t >> 6, l = t & 63;
    int g = (bx - 16400) * 4 + w;
    float2 p = ((const float2*)pos)[g * 64 + l];
    px[w][l] = p.x; py[w][l] = p.y;
    __syncthreads();
    float xi = p.x, yi = p.y;
    u64 m = 0;
    for(int j = 0; j < 64; j++){
      float dx = xi - px[w][j], dy = yi - py[w][j];
      if(dx * dx + dy * dy <= 16.0f) m |= (1ull << j);
    }
    adjm[g * 64 + l] = m;
  } else {
    // s2s step-0 GEMV: z1u = Wih1 @ h0(lb0) + lb1 (lb recomputed inline; weights-only deps)
    for(int i = t; i < 1024; i += 256){
      float zi = bih0[i] + bhh0[i];
      float zg = bih0[2048 + i] + bhh0[2048 + i];
      float zo = bih0[3072 + i] + bhh0[3072 + i];
      float cn = (1.f / (1.f + __expf(-zi))) * tanhf(zg);
      hs[i] = (1.f / (1.f + __expf(-zo))) * tanhf(cn);
    }
    __syncthreads();
    int w = t >> 6, l = t & 63;
    int r = (bx - 16432) * 4 + w;
    const float* wr = Wih1 + (size_t)r * 1024;
    float s = 0.f;
    #pragma unroll
    for(int k = 0; k < 16; k++) s += wr[l + 64 * k] * hs[l + 64 * k];
    for(int o = 32; o; o >>= 1) s += __shfl_xor(s, o);
    if(l == 0) z1u[r] = s + bih1[r] + bhh1[r];
  }
}

// ---------------- 256x256 8-phase counted-vmcnt GEMM ----------------
// MODE 1: relu+bn -> bf16. MODE 3: plain bf16.
#define STAGE_A(buf, half, kt)                                                        \
  { _Pragma("unroll")                                                                 \
    for(int ld = 0; ld < 2; ld++){                                                    \
      int u = ld * 512 + t;                                                           \
      int r = (u >> 3) + (half) * 128, c = u & 7;                                     \
      gl_lds16(A + (size_t)(m0 + r) * K + (kt) * 64 + ((c ^ (r & 7)) << 3),           \
               LA + (buf) * 16384 + ((half) * 1024 + u) * 8);                         \
    } }
#define STAGE_B(buf, half, kt)                                                        \
  { _Pragma("unroll")                                                                 \
    for(int ld = 0; ld < 2; ld++){                                                    \
      int u = ld * 512 + t;                                                           \
      int r = (u >> 3) + (half) * 128, c = u & 7;                                     \
      gl_lds16(Bt + (size_t)(n0 + r) * K + (kt) * 64 + ((c ^ (r & 7)) << 3),          \
               LB + (buf) * 16384 + ((half) * 1024 + u) * 8);                         \
    } }
#define COMPUTE(buf, q)                                                               \
  { if((q) == 0){                                                                     \
      _Pragma("unroll")                                                               \
      for(int nb = 0; nb < 4; nb++)                                                   \
        _Pragma("unroll")                                                             \
        for(int k2 = 0; k2 < 2; k2++){                                                \
          int col = wn + nb * 16 + (l & 15);                                          \
          int kc = k2 * 4 + (l >> 4);                                                 \
          bfr[nb][k2] = Bp[(buf) * 2048 + col * 8 + (kc ^ (col & 7))];                \
        }                                                                             \
    }                                                                                 \
    short8 af[2][2];                                                                  \
    _Pragma("unroll")                                                                 \
    for(int rb = 0; rb < 2; rb++)                                                     \
      _Pragma("unroll")                                                               \
      for(int k2 = 0; k2 < 2; k2++){                                                  \
        int row = wm + (q) * 32 + rb * 16 + (l & 15);                                 \
        int kc = k2 * 4 + (l >> 4);                                                   \
        af[rb][k2] = Ap[(buf) * 2048 + row * 8 + (kc ^ (row & 7))];                   \
      }                                                                               \
    _Pragma("unroll")                                                                 \
    for(int rb = 0; rb < 2; rb++)                                                     \
      _Pragma("unroll")                                                               \
      for(int nb = 0; nb < 4; nb++)                                                   \
        _Pragma("unroll")                                                             \
        for(int k2 = 0; k2 < 2; k2++)                                                 \
          acc[(q) * 2 + rb][nb] = __builtin_amdgcn_mfma_f32_16x16x32_bf16(            \
              af[rb][k2], bfr[nb][k2], acc[(q) * 2 + rb][nb], 0, 0, 0);               \
  }
#define PHASE_BAR() { __builtin_amdgcn_s_barrier(); __builtin_amdgcn_sched_barrier(0); }
#define VM4() { asm volatile("s_waitcnt vmcnt(4)" ::: "memory"); __builtin_amdgcn_sched_barrier(0); }

template<int MODE>
__global__ __launch_bounds__(512, 2) void gemm8p(
    const u16* __restrict__ A, const u16* __restrict__ Bt, u16* __restrict__ Cb,
    const float* __restrict__ p1, const float* __restrict__ p2,
    int M, int N, int K)
{
  __shared__ alignas(16) u16 LA[2 * 16384];
  __shared__ alignas(16) u16 LB[2 * 16384];
  int m0 = blockIdx.x * 256, n0 = blockIdx.y * 256;
  int t = threadIdx.x, w = t >> 6, l = t & 63;
  int wm = (w >> 2) * 128, wn = (w & 3) * 64;
  int nt = K >> 6, ni = nt >> 1;
  f32x4 acc[8][4];
  #pragma unroll
  for(int a = 0; a < 8; a++)
    #pragma unroll
    for(int b = 0; b < 4; b++) acc[a][b] = {0.f, 0.f, 0.f, 0.f};
  short8 bfr[4][2];
  const short8* Ap = (const short8*)LA;
  const short8* Bp = (const short8*)LB;

  STAGE_A(0, 0, 0); STAGE_A(0, 1, 0); STAGE_B(0, 0, 0); STAGE_B(0, 1, 0);
  STAGE_B(1, 0, 1); STAGE_B(1, 1, 1);
  VM4();
  PHASE_BAR();

  for(int i = 0; i < ni; i++){
    int t1 = 2 * i + 1;
    int t2 = (2 * i + 2 < nt) ? 2 * i + 2 : nt - 1;
    int t3 = (2 * i + 3 < nt) ? 2 * i + 3 : nt - 1;
    STAGE_A(1, 0, t1); STAGE_A(1, 1, t1);
    COMPUTE(0, 0);
    PHASE_BAR();
    STAGE_B(0, 0, t2);
    COMPUTE(0, 1);
    PHASE_BAR();
    STAGE_B(0, 1, t2);
    COMPUTE(0, 2);
    PHASE_BAR();
    COMPUTE(0, 3);
    VM4();
    PHASE_BAR();
    STAGE_A(0, 0, t2);
    COMPUTE(1, 0);
    PHASE_BAR();
    STAGE_A(0, 1, t2);
    COMPUTE(1, 1);
    PHASE_BAR();
    STAGE_B(1, 0, t3);
    COMPUTE(1, 2);
    PHASE_BAR();
    STAGE_B(1, 1, t3);
    COMPUTE(1, 3);
    VM4();
    PHASE_BAR();
  }
  asm volatile("s_waitcnt vmcnt(0)" ::: "memory");

  int cc = n0 + wn + (l & 15);
  int r4 = (l >> 4) << 2;
  #pragma unroll
  for(int ar = 0; ar < 8; ar++)
    #pragma unroll
    for(int nb = 0; nb < 4; nb++)
      #pragma unroll
      for(int r = 0; r < 4; r++){
        int row = m0 + wm + ar * 16 + r4 + r, col = cc + nb * 16;
        float v = acc[ar][nb][r];
        if(MODE == 1) v = fmaxf(v, 0.f) * p1[col] + p2[col];
        Cb[(size_t)row * N + col] = f2b(v);
      }
}

// ---------------- split-K skinny GEMM (bf16 B), used for lin2 ----------------
__global__ __launch_bounds__(256) void gemm_sk(
    const u16* __restrict__ A, const u16* __restrict__ Bt, float* __restrict__ Cf,
    int N, int lda, int ldb, int kPer)
{
  constexpr int BM = 128, BN = 64, BK = 64;
  __shared__ alignas(16) u16 Al[BM * BK];
  __shared__ alignas(16) u16 Bl[BN * BK];
  int n0 = blockIdx.x * BN;
  int kb = blockIdx.y * kPer;
  float* C = Cf + (size_t)blockIdx.y * 128 * N;
  int t = threadIdx.x, w = t >> 6, l = t & 63;
  int wm = (w >> 1) * 64, wn = (w & 1) * 32;
  f32x4 acc[4][2];
  for(int a = 0; a < 4; a++) for(int b = 0; b < 2; b++) acc[a][b] = {0.f, 0.f, 0.f, 0.f};

  const short8* Ap = (const short8*)Al;
  const short8* Bp = (const short8*)Bl;

  for(int k0 = kb; k0 < kb + kPer; k0 += BK){
    #pragma unroll
    for(int u = t; u < BM * 8; u += 256){
      int r = u >> 3, c = u & 7;
      gl_lds16(A + (size_t)r * lda + k0 + ((c ^ (r & 7)) << 3), Al + u * 8);
    }
    #pragma unroll
    for(int u = t; u < BN * 8; u += 256){
      int r = u >> 3, c = u & 7;
      gl_lds16(Bt + (size_t)(n0 + r) * ldb + k0 + ((c ^ (r & 7)) << 3), Bl + u * 8);
    }
    __syncthreads();
    #pragma unroll
    for(int ks = 0; ks < 2; ks++){
      int kc = ks * 4 + (l >> 4);
      short8 av[4], bv[2];
      #pragma unroll
      for(int mi = 0; mi < 4; mi++){ int r = wm + mi * 16 + (l & 15); av[mi] = Ap[r * 8 + (kc ^ (r & 7))]; }
      #pragma unroll
      for(int ni = 0; ni < 2; ni++){ int r = wn + ni * 16 + (l & 15); bv[ni] = Bp[r * 8 + (kc ^ (r & 7))]; }
      #pragma unroll
      for(int mi = 0; mi < 4; mi++)
        #pragma unroll
        for(int ni = 0; ni < 2; ni++)
          acc[mi][ni] = __builtin_amdgcn_mfma_f32_16x16x32_bf16(av[mi], bv[ni], acc[mi][ni], 0, 0, 0);
    }
    __syncthreads();
  }

  int cr = wm + ((l >> 4) << 2);
  int cc = n0 + wn + (l & 15);
  for(int mi = 0; mi < 4; mi++)
    for(int ni = 0; ni < 2; ni++)
      for(int r = 0; r < 4; r++)
        C[(size_t)(cr + mi * 16 + r) * N + cc + ni * 16] = acc[mi][ni][r];
}

// ---------------- split-K skinny GEMM with f32 B (in-kernel bf16 conversion) ----------------
__global__ __launch_bounds__(256) void gemm_skf(
    const u16* __restrict__ A, const float* __restrict__ Wih, const float* __restrict__ Whh,
    float* __restrict__ Cf, int N, int lda, int Kih, int Khh, int kPer)
{
  constexpr int BM = 128, BN = 64, BK = 64;
  __shared__ alignas(16) u16 Al[BM * BK];
  __shared__ alignas(16) u16 Bl[BN * BK];
  int n0 = blockIdx.x * BN;
  int kb = blockIdx.y * kPer;
  float* C = Cf + (size_t)blockIdx.y * 128 * N;
  int t = threadIdx.x, w = t >> 6, l = t & 63;
  int wm = (w >> 1) * 64, wn = (w & 1) * 32;
  f32x4 acc[4][2];
  for(int a = 0; a < 4; a++) for(int b = 0; b < 2; b++) acc[a][b] = {0.f, 0.f, 0.f, 0.f};

  const short8* Ap = (const short8*)Al;
  const short8* Bp = (const short8*)Bl;

  for(int k0 = kb; k0 < kb + kPer; k0 += BK){
    #pragma unroll
    for(int u = t; u < BM * 8; u += 256){
      int r = u >> 3, c = u & 7;
      gl_lds16(A + (size_t)r * lda + k0 + ((c ^ (r & 7)) << 3), Al + u * 8);
    }
    #pragma unroll
    for(int u = t; u < BN * 8; u += 256){
      int r = u >> 3, c = u & 7;
      int gk = k0 + c * 8;
      const float* src = (gk < Kih) ? (Wih + (size_t)(n0 + r) * Kih + gk)
                                    : (Whh + (size_t)(n0 + r) * Khh + (gk - Kih));
      float4 v0 = *(const float4*)src;
      float4 v1 = *(const float4*)(src + 4);
      short8 ov;
      ov[0] = (short)f2b(v0.x); ov[1] = (short)f2b(v0.y); ov[2] = (short)f2b(v0.z); ov[3] = (short)f2b(v0.w);
      ov[4] = (short)f2b(v1.x); ov[5] = (short)f2b(v1.y); ov[6] = (short)f2b(v1.z); ov[7] = (short)f2b(v1.w);
      ((short8*)Bl)[r * 8 + (c ^ (r & 7))] = ov;
    }
    __syncthreads();
    #pragma unroll
    for(int ks = 0; ks < 2; ks++){
      int kc = ks * 4 + (l >> 4);
      short8 av[4], bv[2];
      #pragma unroll
      for(int mi = 0; mi < 4; mi++){ int r = wm + mi * 16 + (l & 15); av[mi] = Ap[r * 8 + (kc ^ (r & 7))]; }
      #pragma unroll
      for(int ni = 0; ni < 2; ni++){ int r = wn + ni * 16 + (l & 15); bv[ni] = Bp[r * 8 + (kc ^ (r & 7))]; }
      #pragma unroll
      for(int mi = 0; mi < 4; mi++)
        #pragma unroll
        for(int ni = 0; ni < 2; ni++)
          acc[mi][ni] = __builtin_amdgcn_mfma_f32_16x16x32_bf16(av[mi], bv[ni], acc[mi][ni], 0, 0, 0);
    }
    __syncthreads();
  }

  int cr = wm + ((l >> 4) << 2);
  int cc = n0 + wn + (l & 15);
  for(int mi = 0; mi < 4; mi++)
    for(int ni = 0; ni < 2; ni++)
      for(int r = 0; r < 4; r++)
        C[(size_t)(cr + mi * 16 + r) * N + cc + ni * 16] = acc[mi][ni][r];
}

// ---------------- GAT v3: scores + reg-resident softmax + VALU aggregate ----------------
__global__ __launch_bounds__(256) void gat_attn2(const u64* __restrict__ adjm,
    const u16* __restrict__ h,
    const float* __restrict__ as1, const float* __restrict__ ad1,
    const float* __restrict__ as2, const float* __restrict__ ad2,
    const float* __restrict__ b1, const float* __restrict__ b2,
    u16* __restrict__ x2b){
  int b = blockIdx.x;
  int cv = blockIdx.y >> 3, hh = blockIdx.y & 7;
  __shared__ float hst[64][64];
  __shared__ float esl[64], edl[64];
  __shared__ u64 adjs[64];
  int t = threadIdx.x, w = t >> 6, l = t & 63;
  {
    int j = t >> 2, d0 = (t & 3) * 16;
    const u16* hr = h + (size_t)(b * 64 + j) * 1024 + cv * 512 + hh * 64 + d0;
    #pragma unroll
    for(int k = 0; k < 16; k++) hst[j][d0 + k] = b2f(hr[k]);
  }
  if(t < 64) adjs[t] = adjm[b * 64 + t];
  __syncthreads();
  float aSl = ((cv ? as2 : as1) + hh * 64)[l];
  float aDl = ((cv ? ad2 : ad1) + hh * 64)[l];
  for(int it = 0; it < 16; it++){
    int j = it * 4 + w;
    float v = hst[j][l];
    float ps = v * aSl, pd = v * aDl;
    for(int o = 32; o; o >>= 1){ ps += __shfl_xor(ps, o); pd += __shfl_xor(pd, o); }
    if(l == 0){ esl[j] = ps; edl[j] = pd; }
  }
  __syncthreads();
  float alphaR[16];
  #pragma unroll
  for(int it = 0; it < 16; it++){
    int i = it * 4 + w;
    bool on = (adjs[i] >> l) & 1;
    float e = edl[i] + esl[l];
    e = e > 0.f ? e : 0.2f * e;
    float mx = on ? e : -1e30f;
    for(int o = 32; o; o >>= 1) mx = fmaxf(mx, __shfl_xor(mx, o));
    float p = on ? __expf(e - mx) : 0.f;
    float s = p;
    for(int o = 32; o; o >>= 1) s += __shfl_xor(s, o);
    alphaR[it] = p / s;
  }
  float accv[16];
  #pragma unroll
  for(int k = 0; k < 16; k++) accv[k] = 0.f;
  #pragma unroll
  for(int j = 0; j < 64; j++){
    float hv = hst[j][l];
    #pragma unroll
    for(int it = 0; it < 16; it++){
      float av = __uint_as_float(__builtin_amdgcn_readlane(__float_as_uint(alphaR[it]), j));
      accv[it] += av * hv;
    }
  }
  float bl = ((cv ? b2 : b1) + hh * 64)[l];
  #pragma unroll
  for(int it = 0; it < 16; it++){
    int i = it * 4 + w;
    x2b[(size_t)(b * 64 + i) * 1024 + cv * 512 + hh * 64 + l] = f2b(fmaxf(accv[it] + bl, 0.f));
  }
}

// ---------------- LSTM gates (sum ns split-K partials) ----------------
__global__ void lstm_gate0(const float* __restrict__ zp, const float* __restrict__ lb,
                           float* __restrict__ c, u16* __restrict__ ac0, u16* __restrict__ ac1,
                           int ns){
  int t = blockIdx.x * 256 + threadIdx.x;
  int b = t >> 10, j = t & 1023;
  size_t base = (size_t)b * 4096;
  float zi = 0, zf = 0, zg = 0, zo = 0;
  for(int s = 0; s < ns; s++){
    const float* zr = zp + (size_t)s * 524288 + base;
    zi += zr[j]; zf += zr[1024 + j]; zg += zr[2048 + j]; zo += zr[3072 + j];
  }
  zi += lb[j]; zf += lb[1024 + j]; zg += lb[2048 + j]; zo += lb[3072 + j];
  float ci = c[t];
  float si = 1.f / (1.f + __expf(-zi)), sf = 1.f / (1.f + __expf(-zf)), so = 1.f / (1.f + __expf(-zo));
  float cn = sf * ci + si * tanhf(zg);
  c[t] = cn;
  u16 hb = f2b(so * tanhf(cn));
  ac0[(size_t)b * 3072 + 2048 + j] = hb;
  ac1[(size_t)b * 2048 + j] = hb;
}

__global__ void lstm_gate1(const float* __restrict__ zp, const float* __restrict__ lb,
                           float* __restrict__ c, float* __restrict__ h1f,
                           u16* __restrict__ ac1, u16* __restrict__ ac0, int ns){
  int t = blockIdx.x * 256 + threadIdx.x;
  int b = t >> 10, j = t & 1023;
  size_t base = (size_t)b * 4096;
  float zi = 0, zf = 0, zg = 0, zo = 0;
  for(int s = 0; s < ns; s++){
    const float* zr = zp + (size_t)s * 524288 + base;
    zi += zr[j]; zf += zr[1024 + j]; zg += zr[2048 + j]; zo += zr[3072 + j];
  }
  zi += lb[j]; zf += lb[1024 + j]; zg += lb[2048 + j]; zo += lb[3072 + j];
  float ci = c[t];
  float si = 1.f / (1.f + __expf(-zi)), sf = 1.f / (1.f + __expf(-zf)), so = 1.f / (1.f + __expf(-zo));
  float cn = sf * ci + si * tanhf(zg);
  c[t] = cn;
  float hn = so * tanhf(cn);
  h1f[t] = hn;
  u16 hb = f2b(hn);
  ac1[(size_t)b * 2048 + 1024 + j] = hb;
  ac0[(size_t)b * 3072 + j] = hb;
}

// ---------------- Set2Set attention (bf16 x2) ----------------
template<int STEP>
__global__ __launch_bounds__(256) void s2s_e(const u16* __restrict__ x2b,
    const float* __restrict__ h1, const float* __restrict__ z1u, float* __restrict__ e){
  __shared__ float h1s[1024];
  int t = threadIdx.x, w = t >> 6, l = t & 63;
  int node = blockIdx.x * 4 + w;
  int b = node >> 6;
  for(int i = t; i < 1024; i += 256){
    if(STEP == 0){
      float zi = z1u[i], zg = z1u[2048 + i], zo = z1u[3072 + i];
      float cn = (1.f / (1.f + __expf(-zi))) * tanhf(zg);
      h1s[i] = (1.f / (1.f + __expf(-zo))) * tanhf(cn);
    } else {
      h1s[i] = h1[(size_t)b * 1024 + i];
    }
  }
  __syncthreads();
  const u16* xr = x2b + (size_t)node * 1024;
  float s = 0.f;
  #pragma unroll
  for(int k = 0; k < 16; k++){
    int d = k * 64 + l;
    s += b2f(xr[d]) * h1s[d];
  }
  for(int o = 32; o; o >>= 1) s += __shfl_xor(s, o);
  if(l == 0) e[node] = s;
}

template<int STEP>
__global__ __launch_bounds__(256) void s2s_r(const u16* __restrict__ x2b,
    const float* __restrict__ e, u16* __restrict__ ac0,
    const float* __restrict__ lb0, const float* __restrict__ z1u,
    u16* __restrict__ ac1, float* __restrict__ c0b, float* __restrict__ c1b){
  int b = blockIdx.x, sl = blockIdx.y;
  __shared__ float al[64];
  int t = threadIdx.x;
  if(t < 64){
    float v = e[b * 64 + t];
    float mx = v;
    for(int o = 32; o; o >>= 1) mx = fmaxf(mx, __shfl_xor(mx, o));
    float p = __expf(v - mx);
    float ss = p;
    for(int o = 32; o; o >>= 1) ss += __shfl_xor(ss, o);
    al[t] = p / ss;
  }
  __syncthreads();
  int d = sl * 256 + t;
  const u16* xp = x2b + (size_t)b * 65536 + d;
  float r = 0.f;
  #pragma unroll 8
  for(int j = 0; j < 64; j++) r += al[j] * b2f(xp[j * 1024]);
  ac0[(size_t)b * 3072 + 1024 + d] = f2b(r);
  if(STEP == 0){
    float zi0 = lb0[d], zg0 = lb0[2048 + d], zo0 = lb0[3072 + d];
    float c0 = (1.f / (1.f + __expf(-zi0))) * tanhf(zg0);
    float h0 = (1.f / (1.f + __expf(-zo0))) * tanhf(c0);
    float zi1 = z1u[d], zg1 = z1u[2048 + d], zo1 = z1u[3072 + d];
    float c1 = (1.f / (1.f + __expf(-zi1))) * tanhf(zg1);
    float h1 = (1.f / (1.f + __expf(-zo1))) * tanhf(c1);
    c0b[(size_t)b * 1024 + d] = c0;
    c1b[(size_t)b * 1024 + d] = c1;
    u16 h0b = f2b(h0), h1b = f2b(h1);
    ac0[(size_t)b * 3072 + d] = h1b;
    ac0[(size_t)b * 3072 + 2048 + d] = h0b;
    ac1[(size_t)b * 2048 + d] = h0b;
    ac1[(size_t)b * 2048 + 1024 + d] = h1b;
  }
}

// ---------------- lin2 combine (8 split partials) + bn + relu + lin3 ----------------
__global__ __launch_bounds__(256) void lin3(const float* __restrict__ zp2,
    const float* __restrict__ sc2, const float* __restrict__ sh2,
    const float* __restrict__ W3, const float* __restrict__ b3, float* __restrict__ out){
  int b = blockIdx.x;
  __shared__ float yl[1024];
  int t = threadIdx.x, w = t >> 6, l = t & 63;
  for(int d = t; d < 1024; d += 256){
    float v = 0.f;
    for(int s = 0; s < 8; s++) v += zp2[(size_t)s * 131072 + b * 1024 + d];
    yl[d] = fmaxf(v, 0.f) * sc2[d] + sh2[d];
  }
  __syncthreads();
  for(int n = w; n < 10; n += 4){
    float s = 0.f;
    for(int d = l; d < 1024; d += 64) s += yl[d] * W3[d * 10 + n];
    for(int o = 32; o; o >>= 1) s += __shfl_xor(s, o);
    if(l == 0) out[b * 10 + n] = s + b3[n];
  }
}

extern "C" void kernel_launch(void* const* d_in, const int* in_sizes, int n_in,
                              void* d_out, int out_size, void* d_ws, size_t ws_size,
                              hipStream_t stream){
  const float* x    = (const float*)d_in[0];
  const float* pos  = (const float*)d_in[1];
  const float* W0   = (const float*)d_in[3];
  const float* bn0g = (const float*)d_in[4];
  const float* bn0b = (const float*)d_in[5];
  const float* bn0m = (const float*)d_in[6];
  const float* bn0v = (const float*)d_in[7];
  const float* Wg1  = (const float*)d_in[8];
  const float* as1  = (const float*)d_in[9];
  const float* ad1  = (const float*)d_in[10];
  const float* b1   = (const float*)d_in[11];
  const float* Wg2  = (const float*)d_in[12];
  const float* as2  = (const float*)d_in[13];
  const float* ad2  = (const float*)d_in[14];
  const float* b2   = (const float*)d_in[15];
  const float* Wih0 = (const float*)d_in[16];
  const float* Whh0 = (const float*)d_in[17];
  const float* bih0 = (const float*)d_in[18];
  const float* bhh0 = (const float*)d_in[19];
  const float* Wih1 = (const float*)d_in[20];
  const float* Whh1 = (const float*)d_in[21];
  const float* bih1 = (const float*)d_in[22];
  const float* bhh1 = (const float*)d_in[23];
  const float* W2   = (const float*)d_in[24];
  const float* bn2g = (const float*)d_in[25];
  const float* bn2b = (const float*)d_in[26];
  const float* bn2m = (const float*)d_in[27];
  const float* bn2v = (const float*)d_in[28];
  const float* W3   = (const float*)d_in[29];
  const float* b3   = (const float*)d_in[30];

  char* ws = (char*)d_ws;
  u16*   xbf  = (u16*)(ws + O_XBF);
  u16*   x2b  = (u16*)(ws + O_XBF);
  u16*   w0t  = (u16*)(ws + O_W0T);
  u16*   wgt  = (u16*)(ws + O_WGT);
  u16*   w2t  = (u16*)(ws + O_W2T);
  u16*   xb   = (u16*)(ws + O_XB);
  u16*   hb   = (u16*)(ws + O_H);
  u64*   adjm = (u64*)(ws + O_ADJ);
  float* sc0  = (float*)(ws + O_SC0);
  float* sh0  = (float*)(ws + O_SH0);
  float* sc2  = (float*)(ws + O_SC2);
  float* sh2  = (float*)(ws + O_SH2);
  float* lb0  = (float*)(ws + O_LB0);
  float* lb1  = (float*)(ws + O_LB1);
  float* z1u  = (float*)(ws + O_Z1U);
  char*  s2sb = ws + O_H;
  u16*   ac0  = (u16*)(s2sb + S_AC0);
  u16*   ac1  = (u16*)(s2sb + S_AC1);
  float* c0b  = (float*)(s2sb + S_C0);
  float* c1b  = (float*)(s2sb + S_C1);
  float* h1f  = (float*)(s2sb + S_H1F);
  float* zp   = (float*)(s2sb + S_ZP);
  float* ebuf = (float*)(s2sb + S_E);

  setup_all<<<16688, 256, 0, stream>>>(x, W0, Wg1, Wg2, W2,
                                       bn0g, bn0b, bn0m, bn0v, bn2g, bn2b, bn2m, bn2v,
                                       bih0, bhh0, bih1, bhh1, pos, Wih1,
                                       xbf, w0t, wgt, w2t, sc0, sh0, sc2, sh2, lb0, lb1, adjm, z1u);

  gemm8p<1><<<dim3(32, 8), 512, 0, stream>>>(xbf, w0t, xb, sc0, sh0, 8192, 2048, 2048);
  gemm8p<3><<<dim3(32, 4), 512, 0, stream>>>(xb, wgt, hb, nullptr, nullptr, 8192, 1024, 2048);
  gat_attn2<<<dim3(128, 16), 256, 0, stream>>>(adjm, hb, as1, ad1, as2, ad2, b1, b2, x2b);

  s2s_e<0><<<2048, 256, 0, stream>>>(x2b, nullptr, z1u, ebuf);
  s2s_r<0><<<dim3(128, 4), 256, 0, stream>>>(x2b, ebuf, ac0, lb0, z1u, ac1, c0b, c1b);

  gemm_skf<<<dim3(64, 8), 256, 0, stream>>>(ac0, Wih0, Whh0, zp, 4096, 3072, 2048, 1024, 384);
  lstm_gate0<<<512, 256, 0, stream>>>(zp, lb0, c0b, ac0, ac1, 8);
  gemm_skf<<<dim3(64, 8), 256, 0, stream>>>(ac1, Wih1, Whh1, zp, 4096, 2048, 1024, 1024, 256);
  lstm_gate1<<<512, 256, 0, stream>>>(zp, lb1, c1b, h1f, ac1, ac0, 8);
  s2s_e<1><<<2048, 256, 0, stream>>>(x2b, h1f, nullptr, ebuf);
  s2s_r<1><<<dim3(128, 4), 256, 0, stream>>>(x2b, ebuf, ac0, nullptr, nullptr, nullptr, nullptr, nullptr);

  gemm_sk<<<dim3(16, 8), 256, 0, stream>>>(ac0, w2t, zp, 1024, 3072, 2048, 256);
  lin3<<<128, 256, 0, stream>>>(zp, sc2, sh2, W3, b3, (float*)d_out);
}

// Round 19
// 276.493 us; speedup vs baseline: 1.0441x; 1.0441x over previous
//
#include <hip/hip_runtime.h>
#include <hip/hip_bf16.h>

typedef unsigned short u16;
typedef __attribute__((ext_vector_type(8))) short short8;
typedef __attribute__((ext_vector_type(4))) float f32x4;
typedef unsigned long long u64;

#define DI __device__ __forceinline__

DI u16 f2b(float f){
  unsigned u = __float_as_uint(f);
  unsigned r = 0x7fffu + ((u >> 16) & 1u);
  return (u16)((u + r) >> 16);
}
DI float b2f(u16 u){ return __uint_as_float((unsigned)u << 16); }

DI void gl_lds16(const void* g, void* l){
  __builtin_amdgcn_global_load_lds((const __attribute__((address_space(1))) void*)g,
                                   (__attribute__((address_space(3))) void*)l, 16, 0, 0);
}

// ---------------- workspace layout (bytes) ----------------
constexpr size_t O_XBF = 0;
constexpr size_t O_W0T = O_XBF + 33554432;
constexpr size_t O_WGT = O_W0T + 8388608;
constexpr size_t O_W2T = O_WGT + 4194304;
constexpr size_t O_XB  = O_W2T + 4194304;
constexpr size_t O_H   = O_XB  + 33554432;
constexpr size_t O_ES  = O_H   + 33554432;
constexpr size_t O_ED  = O_ES  + 524288;
constexpr size_t O_ADJ = O_ED  + 524288;
constexpr size_t O_SC0 = O_ADJ + 65536;
constexpr size_t O_SH0 = O_SC0 + 8192;
constexpr size_t O_SC2 = O_SH0 + 8192;
constexpr size_t O_SH2 = O_SC2 + 4096;
constexpr size_t O_LB0 = O_SH2 + 4096;
constexpr size_t O_LB1 = O_LB0 + 16384;
constexpr size_t S_AC0 = 0;
constexpr size_t S_AC1 = S_AC0 + 786432;
constexpr size_t S_C0  = S_AC1 + 524288;
constexpr size_t S_C1  = S_C0  + 524288;
constexpr size_t S_H1F = S_C1  + 524288;
constexpr size_t S_ZP  = S_H1F + 524288;
constexpr size_t S_E   = S_ZP  + 16777216;
constexpr size_t S_Z1U = S_E   + 32768;

// ---------------- one setup kernel: x cvt + 4 transposes + prep + adjacency ----------------
__global__ __launch_bounds__(256) void setup_all(
    const float* __restrict__ x,
    const float* __restrict__ W0, const float* __restrict__ Wg1,
    const float* __restrict__ Wg2, const float* __restrict__ W2,
    const float* __restrict__ g0, const float* __restrict__ b0, const float* __restrict__ m0, const float* __restrict__ v0,
    const float* __restrict__ g2, const float* __restrict__ b2, const float* __restrict__ m2, const float* __restrict__ v2,
    const float* __restrict__ bih0, const float* __restrict__ bhh0,
    const float* __restrict__ bih1, const float* __restrict__ bhh1,
    const float* __restrict__ pos,
    u16* __restrict__ xbf, u16* __restrict__ w0t, u16* __restrict__ wgt, u16* __restrict__ w2t,
    float* __restrict__ sc0, float* __restrict__ sh0, float* __restrict__ sc2, float* __restrict__ sh2,
    float* __restrict__ lb0, float* __restrict__ lb1, u64* __restrict__ adjm)
{
  __shared__ float tile[32][33];
  __shared__ float px[4][64], py[4][64];
  int bx = blockIdx.x, t = threadIdx.x;
  if(bx < 8192){
    int idx = bx * 256 + t;
    int r = idx >> 8, c8 = (idx & 255) << 3;
    const float* src = x + (size_t)r * 2048 + c8;
    float4 v0 = *(const float4*)src;
    float4 v1 = *(const float4*)(src + 4);
    short8 ov;
    ov[0] = (short)f2b(v0.x); ov[1] = (short)f2b(v0.y); ov[2] = (short)f2b(v0.z); ov[3] = (short)f2b(v0.w);
    ov[4] = (short)f2b(v1.x); ov[5] = (short)f2b(v1.y); ov[6] = (short)f2b(v1.z); ov[7] = (short)f2b(v1.w);
    *(short8*)(xbf + (size_t)r * 2048 + c8) = ov;
  } else if(bx < 16384){
    int bx2 = bx - 8192;
    int cx = bx2 & 127, by = bx2 >> 7;
    const float* src; u16* dst; int C, droff;
    if(cx < 64){      src = W0;  dst = w0t; C = 2048; droff = 0; }
    else if(cx < 80){ src = Wg1; dst = wgt; C = 512;  droff = 0;   cx -= 64; }
    else if(cx < 96){ src = Wg2; dst = wgt; C = 512;  droff = 512; cx -= 80; }
    else {            src = W2;  dst = w2t; C = 1024; droff = 0;   cx -= 96; }
    int c0 = cx * 32, r0 = by * 32;
    int tx = t & 31, ty = t >> 5;
    for(int i = 0; i < 4; i++)
      tile[ty + 8*i][tx] = src[(size_t)(r0 + ty + 8*i) * C + c0 + tx];
    __syncthreads();
    for(int i = 0; i < 4; i++)
      dst[(size_t)(droff + c0 + ty + 8*i) * 2048 + r0 + tx] = f2b(tile[tx][ty + 8*i]);
  } else if(bx < 16400){
    int tt = (bx - 16384) * 256 + t;
    if(tt < 2048){ float s = g0[tt] * rsqrtf(v0[tt] + 0.1f); sc0[tt] = s; sh0[tt] = b0[tt] - m0[tt] * s; }
    if(tt < 1024){ float s = g2[tt] * rsqrtf(v2[tt] + 0.1f); sc2[tt] = s; sh2[tt] = b2[tt] - m2[tt] * s; }
    lb0[tt] = bih0[tt] + bhh0[tt];
    lb1[tt] = bih1[tt] + bhh1[tt];
  } else {
    int w = t >> 6, l = t & 63;
    int g = (bx - 16400) * 4 + w;
    float2 p = ((const float2*)pos)[g * 64 + l];
    px[w][l] = p.x; py[w][l] = p.y;
    __syncthreads();
    float xi = p.x, yi = p.y;
    u64 m = 0;
    for(int j = 0; j < 64; j++){
      float dx = xi - px[w][j], dy = yi - py[w][j];
      if(dx * dx + dy * dy <= 16.0f) m |= (1ull << j);
    }
    adjm[g * 64 + l] = m;
  }
}

// ---------------- 256x256 8-phase counted-vmcnt GEMM (GEMM1) ----------------
#define STAGE_A(buf, half, kt)                                                        \
  { _Pragma("unroll")                                                                 \
    for(int ld = 0; ld < 2; ld++){                                                    \
      int u = ld * 512 + t;                                                           \
      int r = (u >> 3) + (half) * 128, c = u & 7;                                     \
      gl_lds16(A + (size_t)(m0 + r) * K + (kt) * 64 + ((c ^ (r & 7)) << 3),           \
               LA + (buf) * 16384 + ((half) * 1024 + u) * 8);                         \
    } }
#define STAGE_B(buf, half, kt)                                                        \
  { _Pragma("unroll")                                                                 \
    for(int ld = 0; ld < 2; ld++){                                                    \
      int u = ld * 512 + t;                                                           \
      int r = (u >> 3) + (half) * 128, c = u & 7;                                     \
      gl_lds16(Bt + (size_t)(n0 + r) * K + (kt) * 64 + ((c ^ (r & 7)) << 3),          \
               LB + (buf) * 16384 + ((half) * 1024 + u) * 8);                         \
    } }
#define COMPUTE(buf, q)                                                               \
  { if((q) == 0){                                                                     \
      _Pragma("unroll")                                                               \
      for(int nb = 0; nb < 4; nb++)                                                   \
        _Pragma("unroll")                                                             \
        for(int k2 = 0; k2 < 2; k2++){                                                \
          int col = wn + nb * 16 + (l & 15);                                          \
          int kc = k2 * 4 + (l >> 4);                                                 \
          bfr[nb][k2] = Bp[(buf) * 2048 + col * 8 + (kc ^ (col & 7))];                \
        }                                                                             \
    }                                                                                 \
    short8 af[2][2];                                                                  \
    _Pragma("unroll")                                                                 \
    for(int rb = 0; rb < 2; rb++)                                                     \
      _Pragma("unroll")                                                               \
      for(int k2 = 0; k2 < 2; k2++){                                                  \
        int row = wm + (q) * 32 + rb * 16 + (l & 15);                                 \
        int kc = k2 * 4 + (l >> 4);                                                   \
        af[rb][k2] = Ap[(buf) * 2048 + row * 8 + (kc ^ (row & 7))];                   \
      }                                                                               \
    _Pragma("unroll")                                                                 \
    for(int rb = 0; rb < 2; rb++)                                                     \
      _Pragma("unroll")                                                               \
      for(int nb = 0; nb < 4; nb++)                                                   \
        _Pragma("unroll")                                                             \
        for(int k2 = 0; k2 < 2; k2++)                                                 \
          acc[(q) * 2 + rb][nb] = __builtin_amdgcn_mfma_f32_16x16x32_bf16(            \
              af[rb][k2], bfr[nb][k2], acc[(q) * 2 + rb][nb], 0, 0, 0);               \
  }
#define PHASE_BAR() { __builtin_amdgcn_s_barrier(); __builtin_amdgcn_sched_barrier(0); }
#define VM4() { asm volatile("s_waitcnt vmcnt(4)" ::: "memory"); __builtin_amdgcn_sched_barrier(0); }

__global__ __launch_bounds__(512, 2) void gemm8p(
    const u16* __restrict__ A, const u16* __restrict__ Bt, u16* __restrict__ Cb,
    const float* __restrict__ p1, const float* __restrict__ p2,
    int M, int N, int K)
{
  __shared__ alignas(16) u16 LA[2 * 16384];
  __shared__ alignas(16) u16 LB[2 * 16384];
  int m0 = blockIdx.x * 256, n0 = blockIdx.y * 256;
  int t = threadIdx.x, w = t >> 6, l = t & 63;
  int wm = (w >> 2) * 128, wn = (w & 3) * 64;
  int nt = K >> 6, ni = nt >> 1;
  f32x4 acc[8][4];
  #pragma unroll
  for(int a = 0; a < 8; a++)
    #pragma unroll
    for(int b = 0; b < 4; b++) acc[a][b] = {0.f, 0.f, 0.f, 0.f};
  short8 bfr[4][2];
  const short8* Ap = (const short8*)LA;
  const short8* Bp = (const short8*)LB;

  STAGE_A(0, 0, 0); STAGE_A(0, 1, 0); STAGE_B(0, 0, 0); STAGE_B(0, 1, 0);
  STAGE_B(1, 0, 1); STAGE_B(1, 1, 1);
  VM4();
  PHASE_BAR();

  for(int i = 0; i < ni; i++){
    int t1 = 2 * i + 1;
    int t2 = (2 * i + 2 < nt) ? 2 * i + 2 : nt - 1;
    int t3 = (2 * i + 3 < nt) ? 2 * i + 3 : nt - 1;
    STAGE_A(1, 0, t1); STAGE_A(1, 1, t1);
    COMPUTE(0, 0);
    PHASE_BAR();
    STAGE_B(0, 0, t2);
    COMPUTE(0, 1);
    PHASE_BAR();
    STAGE_B(0, 1, t2);
    COMPUTE(0, 2);
    PHASE_BAR();
    COMPUTE(0, 3);
    VM4();
    PHASE_BAR();
    STAGE_A(0, 0, t2);
    COMPUTE(1, 0);
    PHASE_BAR();
    STAGE_A(0, 1, t2);
    COMPUTE(1, 1);
    PHASE_BAR();
    STAGE_B(1, 0, t3);
    COMPUTE(1, 2);
    PHASE_BAR();
    STAGE_B(1, 1, t3);
    COMPUTE(1, 3);
    VM4();
    PHASE_BAR();
  }
  asm volatile("s_waitcnt vmcnt(0)" ::: "memory");

  int cc = n0 + wn + (l & 15);
  int r4 = (l >> 4) << 2;
  #pragma unroll
  for(int ar = 0; ar < 8; ar++)
    #pragma unroll
    for(int nb = 0; nb < 4; nb++)
      #pragma unroll
      for(int r = 0; r < 4; r++){
        int row = m0 + wm + ar * 16 + r4 + r, col = cc + nb * 16;
        float v = acc[ar][nb][r];
        v = fmaxf(v, 0.f) * p1[col] + p2[col];
        Cb[(size_t)row * N + col] = f2b(v);
      }
}

// ---------------- bf16 MFMA GEMM (m97 structure; GEMM2: plain bf16 out) ----------------
__global__ __launch_bounds__(256) void gemm_bf16(
    const u16* __restrict__ A, const u16* __restrict__ Bt, u16* __restrict__ Cb,
    int M, int N, int K)
{
  constexpr int BM = 128, BN = 128, BK = 64;
  __shared__ alignas(16) u16 Al[BM * BK];
  __shared__ alignas(16) u16 Bl[BN * BK];
  int m0 = blockIdx.x * BM, n0 = blockIdx.y * BN;
  int t = threadIdx.x, w = t >> 6, l = t & 63;
  int wm = (w >> 1) * 64, wn = (w & 1) * 64;
  f32x4 acc[4][4];
  for(int a = 0; a < 4; a++) for(int b = 0; b < 4; b++) acc[a][b] = {0.f, 0.f, 0.f, 0.f};

  const short8* Ap = (const short8*)Al;
  const short8* Bp = (const short8*)Bl;

  for(int k0 = 0; k0 < K; k0 += BK){
    #pragma unroll
    for(int u = t; u < BM * 8; u += 256){
      int r = u >> 3, c = u & 7;
      gl_lds16(A + (size_t)(m0 + r) * K + k0 + ((c ^ (r & 7)) << 3), Al + u * 8);
    }
    #pragma unroll
    for(int u = t; u < BN * 8; u += 256){
      int r = u >> 3, c = u & 7;
      gl_lds16(Bt + (size_t)(n0 + r) * K + k0 + ((c ^ (r & 7)) << 3), Bl + u * 8);
    }
    __syncthreads();
    #pragma unroll
    for(int ks = 0; ks < 2; ks++){
      int kc = ks * 4 + (l >> 4);
      short8 av[4], bv[4];
      #pragma unroll
      for(int mi = 0; mi < 4; mi++){ int r = wm + mi * 16 + (l & 15); av[mi] = Ap[r * 8 + (kc ^ (r & 7))]; }
      #pragma unroll
      for(int ni = 0; ni < 4; ni++){ int r = wn + ni * 16 + (l & 15); bv[ni] = Bp[r * 8 + (kc ^ (r & 7))]; }
      #pragma unroll
      for(int mi = 0; mi < 4; mi++)
        #pragma unroll
        for(int ni = 0; ni < 4; ni++)
          acc[mi][ni] = __builtin_amdgcn_mfma_f32_16x16x32_bf16(av[mi], bv[ni], acc[mi][ni], 0, 0, 0);
    }
    __syncthreads();
  }

  int cr = m0 + wm + ((l >> 4) << 2);
  int cc = n0 + wn + (l & 15);
  for(int mi = 0; mi < 4; mi++)
    for(int ni = 0; ni < 4; ni++)
      for(int r = 0; r < 4; r++){
        int row = cr + mi * 16 + r, col = cc + ni * 16;
        Cb[(size_t)row * N + col] = f2b(acc[mi][ni][r]);
      }
}

// ---------------- split-K skinny GEMM (bf16 B), used for lin2 ----------------
__global__ __launch_bounds__(256) void gemm_sk(
    const u16* __restrict__ A, const u16* __restrict__ Bt, float* __restrict__ Cf,
    int N, int lda, int ldb, int kPer)
{
  constexpr int BM = 128, BN = 64, BK = 64;
  __shared__ alignas(16) u16 Al[BM * BK];
  __shared__ alignas(16) u16 Bl[BN * BK];
  int n0 = blockIdx.x * BN;
  int kb = blockIdx.y * kPer;
  float* C = Cf + (size_t)blockIdx.y * 128 * N;
  int t = threadIdx.x, w = t >> 6, l = t & 63;
  int wm = (w >> 1) * 64, wn = (w & 1) * 32;
  f32x4 acc[4][2];
  for(int a = 0; a < 4; a++) for(int b = 0; b < 2; b++) acc[a][b] = {0.f, 0.f, 0.f, 0.f};

  const short8* Ap = (const short8*)Al;
  const short8* Bp = (const short8*)Bl;

  for(int k0 = kb; k0 < kb + kPer; k0 += BK){
    #pragma unroll
    for(int u = t; u < BM * 8; u += 256){
      int r = u >> 3, c = u & 7;
      gl_lds16(A + (size_t)r * lda + k0 + ((c ^ (r & 7)) << 3), Al + u * 8);
    }
    #pragma unroll
    for(int u = t; u < BN * 8; u += 256){
      int r = u >> 3, c = u & 7;
      gl_lds16(Bt + (size_t)(n0 + r) * ldb + k0 + ((c ^ (r & 7)) << 3), Bl + u * 8);
    }
    __syncthreads();
    #pragma unroll
    for(int ks = 0; ks < 2; ks++){
      int kc = ks * 4 + (l >> 4);
      short8 av[4], bv[2];
      #pragma unroll
      for(int mi = 0; mi < 4; mi++){ int r = wm + mi * 16 + (l & 15); av[mi] = Ap[r * 8 + (kc ^ (r & 7))]; }
      #pragma unroll
      for(int ni = 0; ni < 2; ni++){ int r = wn + ni * 16 + (l & 15); bv[ni] = Bp[r * 8 + (kc ^ (r & 7))]; }
      #pragma unroll
      for(int mi = 0; mi < 4; mi++)
        #pragma unroll
        for(int ni = 0; ni < 2; ni++)
          acc[mi][ni] = __builtin_amdgcn_mfma_f32_16x16x32_bf16(av[mi], bv[ni], acc[mi][ni], 0, 0, 0);
    }
    __syncthreads();
  }

  int cr = wm + ((l >> 4) << 2);
  int cc = n0 + wn + (l & 15);
  for(int mi = 0; mi < 4; mi++)
    for(int ni = 0; ni < 2; ni++)
      for(int r = 0; r < 4; r++)
        C[(size_t)(cr + mi * 16 + r) * N + cc + ni * 16] = acc[mi][ni][r];
}

// ---------------- split-K skinny GEMM with f32 B (in-kernel bf16 conversion) ----------------
__global__ __launch_bounds__(256) void gemm_skf(
    const u16* __restrict__ A, const float* __restrict__ Wih, const float* __restrict__ Whh,
    float* __restrict__ Cf, int N, int lda, int Kih, int Khh, int kPer)
{
  constexpr int BM = 128, BN = 64, BK = 64;
  __shared__ alignas(16) u16 Al[BM * BK];
  __shared__ alignas(16) u16 Bl[BN * BK];
  int n0 = blockIdx.x * BN;
  int kb = blockIdx.y * kPer;
  float* C = Cf + (size_t)blockIdx.y * 128 * N;
  int t = threadIdx.x, w = t >> 6, l = t & 63;
  int wm = (w >> 1) * 64, wn = (w & 1) * 32;
  f32x4 acc[4][2];
  for(int a = 0; a < 4; a++) for(int b = 0; b < 2; b++) acc[a][b] = {0.f, 0.f, 0.f, 0.f};

  const short8* Ap = (const short8*)Al;
  const short8* Bp = (const short8*)Bl;

  for(int k0 = kb; k0 < kb + kPer; k0 += BK){
    #pragma unroll
    for(int u = t; u < BM * 8; u += 256){
      int r = u >> 3, c = u & 7;
      gl_lds16(A + (size_t)r * lda + k0 + ((c ^ (r & 7)) << 3), Al + u * 8);
    }
    #pragma unroll
    for(int u = t; u < BN * 8; u += 256){
      int r = u >> 3, c = u & 7;
      int gk = k0 + c * 8;
      const float* src = (gk < Kih) ? (Wih + (size_t)(n0 + r) * Kih + gk)
                                    : (Whh + (size_t)(n0 + r) * Khh + (gk - Kih));
      float4 v0 = *(const float4*)src;
      float4 v1 = *(const float4*)(src + 4);
      short8 ov;
      ov[0] = (short)f2b(v0.x); ov[1] = (short)f2b(v0.y); ov[2] = (short)f2b(v0.z); ov[3] = (short)f2b(v0.w);
      ov[4] = (short)f2b(v1.x); ov[5] = (short)f2b(v1.y); ov[6] = (short)f2b(v1.z); ov[7] = (short)f2b(v1.w);
      ((short8*)Bl)[r * 8 + (c ^ (r & 7))] = ov;
    }
    __syncthreads();
    #pragma unroll
    for(int ks = 0; ks < 2; ks++){
      int kc = ks * 4 + (l >> 4);
      short8 av[4], bv[2];
      #pragma unroll
      for(int mi = 0; mi < 4; mi++){ int r = wm + mi * 16 + (l & 15); av[mi] = Ap[r * 8 + (kc ^ (r & 7))]; }
      #pragma unroll
      for(int ni = 0; ni < 2; ni++){ int r = wn + ni * 16 + (l & 15); bv[ni] = Bp[r * 8 + (kc ^ (r & 7))]; }
      #pragma unroll
      for(int mi = 0; mi < 4; mi++)
        #pragma unroll
        for(int ni = 0; ni < 2; ni++)
          acc[mi][ni] = __builtin_amdgcn_mfma_f32_16x16x32_bf16(av[mi], bv[ni], acc[mi][ni], 0, 0, 0);
    }
    __syncthreads();
  }

  int cr = wm + ((l >> 4) << 2);
  int cc = n0 + wn + (l & 15);
  for(int mi = 0; mi < 4; mi++)
    for(int ni = 0; ni < 2; ni++)
      for(int r = 0; r < 4; r++)
        C[(size_t)(cr + mi * 16 + r) * N + cc + ni * 16] = acc[mi][ni][r];
}

// ---------------- GAT v3: scores + reg-resident softmax + VALU aggregate ----------------
__global__ __launch_bounds__(256) void gat_attn2(const u64* __restrict__ adjm,
    const u16* __restrict__ h,
    const float* __restrict__ as1, const float* __restrict__ ad1,
    const float* __restrict__ as2, const float* __restrict__ ad2,
    const float* __restrict__ b1, const float* __restrict__ b2,
    u16* __restrict__ x2b){
  int b = blockIdx.x;
  int cv = blockIdx.y >> 3, hh = blockIdx.y & 7;
  __shared__ float hst[64][64];
  __shared__ float esl[64], edl[64];
  __shared__ u64 adjs[64];
  int t = threadIdx.x, w = t >> 6, l = t & 63;
  {
    int j = t >> 2, d0 = (t & 3) * 16;
    const u16* hr = h + (size_t)(b * 64 + j) * 1024 + cv * 512 + hh * 64 + d0;
    #pragma unroll
    for(int k = 0; k < 16; k++) hst[j][d0 + k] = b2f(hr[k]);
  }
  if(t < 64) adjs[t] = adjm[b * 64 + t];
  __syncthreads();
  float aSl = ((cv ? as2 : as1) + hh * 64)[l];
  float aDl = ((cv ? ad2 : ad1) + hh * 64)[l];
  for(int it = 0; it < 16; it++){
    int j = it * 4 + w;
    float v = hst[j][l];
    float ps = v * aSl, pd = v * aDl;
    for(int o = 32; o; o >>= 1){ ps += __shfl_xor(ps, o); pd += __shfl_xor(pd, o); }
    if(l == 0){ esl[j] = ps; edl[j] = pd; }
  }
  __syncthreads();
  float alphaR[16];
  #pragma unroll
  for(int it = 0; it < 16; it++){
    int i = it * 4 + w;
    bool on = (adjs[i] >> l) & 1;
    float e = edl[i] + esl[l];
    e = e > 0.f ? e : 0.2f * e;
    float mx = on ? e : -1e30f;
    for(int o = 32; o; o >>= 1) mx = fmaxf(mx, __shfl_xor(mx, o));
    float p = on ? __expf(e - mx) : 0.f;
    float s = p;
    for(int o = 32; o; o >>= 1) s += __shfl_xor(s, o);
    alphaR[it] = p / s;
  }
  float accv[16];
  #pragma unroll
  for(int k = 0; k < 16; k++) accv[k] = 0.f;
  #pragma unroll
  for(int j = 0; j < 64; j++){
    float hv = hst[j][l];
    #pragma unroll
    for(int it = 0; it < 16; it++){
      float av = __uint_as_float(__builtin_amdgcn_readlane(__float_as_uint(alphaR[it]), j));
      accv[it] += av * hv;
    }
  }
  float bl = ((cv ? b2 : b1) + hh * 64)[l];
  #pragma unroll
  for(int it = 0; it < 16; it++){
    int i = it * 4 + w;
    x2b[(size_t)(b * 64 + i) * 1024 + cv * 512 + hh * 64 + l] = f2b(fmaxf(accv[it] + bl, 0.f));
  }
}

// ---------------- Set2Set step-0 shortcut ----------------
__global__ __launch_bounds__(256) void s2s0_gemv(const float* __restrict__ Wih1,
    const float* __restrict__ lb1, const float* __restrict__ lb0, float* __restrict__ z1u){
  __shared__ float hs[1024];
  int t = threadIdx.x;
  for(int i = t; i < 1024; i += 256){
    float zi = lb0[i], zg = lb0[2048 + i], zo = lb0[3072 + i];
    float cn = (1.f / (1.f + __expf(-zi))) * tanhf(zg);
    hs[i] = (1.f / (1.f + __expf(-zo))) * tanhf(cn);
  }
  __syncthreads();
  int w = t >> 6, l = t & 63;
  int r = blockIdx.x * 4 + w;
  const float* wr = Wih1 + (size_t)r * 1024;
  float s = 0.f;
  #pragma unroll
  for(int k = 0; k < 16; k++) s += wr[l + 64 * k] * hs[l + 64 * k];
  for(int o = 32; o; o >>= 1) s += __shfl_xor(s, o);
  if(l == 0) z1u[r] = s + lb1[r];
}

// ---------------- LSTM gates (sum ns split-K partials) ----------------
__global__ void lstm_gate0(const float* __restrict__ zp, const float* __restrict__ lb,
                           float* __restrict__ c, u16* __restrict__ ac0, u16* __restrict__ ac1,
                           int ns){
  int t = blockIdx.x * 256 + threadIdx.x;
  int b = t >> 10, j = t & 1023;
  size_t base = (size_t)b * 4096;
  float zi = 0, zf = 0, zg = 0, zo = 0;
  for(int s = 0; s < ns; s++){
    const float* zr = zp + (size_t)s * 524288 + base;
    zi += zr[j]; zf += zr[1024 + j]; zg += zr[2048 + j]; zo += zr[3072 + j];
  }
  zi += lb[j]; zf += lb[1024 + j]; zg += lb[2048 + j]; zo += lb[3072 + j];
  float ci = c[t];
  float si = 1.f / (1.f + __expf(-zi)), sf = 1.f / (1.f + __expf(-zf)), so = 1.f / (1.f + __expf(-zo));
  float cn = sf * ci + si * tanhf(zg);
  c[t] = cn;
  u16 hb = f2b(so * tanhf(cn));
  ac0[(size_t)b * 3072 + 2048 + j] = hb;
  ac1[(size_t)b * 2048 + j] = hb;
}

__global__ void lstm_gate1(const float* __restrict__ zp, const float* __restrict__ lb,
                           float* __restrict__ c, float* __restrict__ h1f,
                           u16* __restrict__ ac1, u16* __restrict__ ac0, int ns){
  int t = blockIdx.x * 256 + threadIdx.x;
  int b = t >> 10, j = t & 1023;
  size_t base = (size_t)b * 4096;
  float zi = 0, zf = 0, zg = 0, zo = 0;
  for(int s = 0; s < ns; s++){
    const float* zr = zp + (size_t)s * 524288 + base;
    zi += zr[j]; zf += zr[1024 + j]; zg += zr[2048 + j]; zo += zr[3072 + j];
  }
  zi += lb[j]; zf += lb[1024 + j]; zg += lb[2048 + j]; zo += lb[3072 + j];
  float ci = c[t];
  float si = 1.f / (1.f + __expf(-zi)), sf = 1.f / (1.f + __expf(-zf)), so = 1.f / (1.f + __expf(-zo));
  float cn = sf * ci + si * tanhf(zg);
  c[t] = cn;
  float hn = so * tanhf(cn);
  h1f[t] = hn;
  u16 hb = f2b(hn);
  ac1[(size_t)b * 2048 + 1024 + j] = hb;
  ac0[(size_t)b * 3072 + j] = hb;
}

// ---------------- Set2Set attention (bf16 x2) ----------------
template<int STEP>
__global__ __launch_bounds__(256) void s2s_e(const u16* __restrict__ x2b,
    const float* __restrict__ h1, const float* __restrict__ z1u, float* __restrict__ e){
  __shared__ float h1s[1024];
  int t = threadIdx.x, w = t >> 6, l = t & 63;
  int node = blockIdx.x * 4 + w;
  int b = node >> 6;
  for(int i = t; i < 1024; i += 256){
    if(STEP == 0){
      float zi = z1u[i], zg = z1u[2048 + i], zo = z1u[3072 + i];
      float cn = (1.f / (1.f + __expf(-zi))) * tanhf(zg);
      h1s[i] = (1.f / (1.f + __expf(-zo))) * tanhf(cn);
    } else {
      h1s[i] = h1[(size_t)b * 1024 + i];
    }
  }
  __syncthreads();
  const u16* xr = x2b + (size_t)node * 1024;
  float s = 0.f;
  #pragma unroll
  for(int k = 0; k < 16; k++){
    int d = k * 64 + l;
    s += b2f(xr[d]) * h1s[d];
  }
  for(int o = 32; o; o >>= 1) s += __shfl_xor(s, o);
  if(l == 0) e[node] = s;
}

template<int STEP>
__global__ __launch_bounds__(256) void s2s_r(const u16* __restrict__ x2b,
    const float* __restrict__ e, u16* __restrict__ ac0,
    const float* __restrict__ lb0, const float* __restrict__ z1u,
    u16* __restrict__ ac1, float* __restrict__ c0b, float* __restrict__ c1b){
  int b = blockIdx.x, sl = blockIdx.y;
  __shared__ float al[64];
  int t = threadIdx.x;
  if(t < 64){
    float v = e[b * 64 + t];
    float mx = v;
    for(int o = 32; o; o >>= 1) mx = fmaxf(mx, __shfl_xor(mx, o));
    float p = __expf(v - mx);
    float ss = p;
    for(int o = 32; o; o >>= 1) ss += __shfl_xor(ss, o);
    al[t] = p / ss;
  }
  __syncthreads();
  int d = sl * 256 + t;
  const u16* xp = x2b + (size_t)b * 65536 + d;
  float r = 0.f;
  #pragma unroll 8
  for(int j = 0; j < 64; j++) r += al[j] * b2f(xp[j * 1024]);
  ac0[(size_t)b * 3072 + 1024 + d] = f2b(r);
  if(STEP == 0){
    float zi0 = lb0[d], zg0 = lb0[2048 + d], zo0 = lb0[3072 + d];
    float c0 = (1.f / (1.f + __expf(-zi0))) * tanhf(zg0);
    float h0 = (1.f / (1.f + __expf(-zo0))) * tanhf(c0);
    float zi1 = z1u[d], zg1 = z1u[2048 + d], zo1 = z1u[3072 + d];
    float c1 = (1.f / (1.f + __expf(-zi1))) * tanhf(zg1);
    float h1 = (1.f / (1.f + __expf(-zo1))) * tanhf(c1);
    c0b[(size_t)b * 1024 + d] = c0;
    c1b[(size_t)b * 1024 + d] = c1;
    u16 h0b = f2b(h0), h1b = f2b(h1);
    ac0[(size_t)b * 3072 + d] = h1b;
    ac0[(size_t)b * 3072 + 2048 + d] = h0b;
    ac1[(size_t)b * 2048 + d] = h0b;
    ac1[(size_t)b * 2048 + 1024 + d] = h1b;
  }
}

// ---------------- lin2 combine (8 split partials) + bn + relu + lin3 ----------------
__global__ __launch_bounds__(256) void lin3(const float* __restrict__ zp2,
    const float* __restrict__ sc2, const float* __restrict__ sh2,
    const float* __restrict__ W3, const float* __restrict__ b3, float* __restrict__ out){
  int b = blockIdx.x;
  __shared__ float yl[1024];
  int t = threadIdx.x, w = t >> 6, l = t & 63;
  for(int d = t; d < 1024; d += 256){
    float v = 0.f;
    for(int s = 0; s < 8; s++) v += zp2[(size_t)s * 131072 + b * 1024 + d];
    yl[d] = fmaxf(v, 0.f) * sc2[d] + sh2[d];
  }
  __syncthreads();
  for(int n = w; n < 10; n += 4){
    float s = 0.f;
    for(int d = l; d < 1024; d += 64) s += yl[d] * W3[d * 10 + n];
    for(int o = 32; o; o >>= 1) s += __shfl_xor(s, o);
    if(l == 0) out[b * 10 + n] = s + b3[n];
  }
}

extern "C" void kernel_launch(void* const* d_in, const int* in_sizes, int n_in,
                              void* d_out, int out_size, void* d_ws, size_t ws_size,
                              hipStream_t stream){
  const float* x    = (const float*)d_in[0];
  const float* pos  = (const float*)d_in[1];
  const float* W0   = (const float*)d_in[3];
  const float* bn0g = (const float*)d_in[4];
  const float* bn0b = (const float*)d_in[5];
  const float* bn0m = (const float*)d_in[6];
  const float* bn0v = (const float*)d_in[7];
  const float* Wg1  = (const float*)d_in[8];
  const float* as1  = (const float*)d_in[9];
  const float* ad1  = (const float*)d_in[10];
  const float* b1   = (const float*)d_in[11];
  const float* Wg2  = (const float*)d_in[12];
  const float* as2  = (const float*)d_in[13];
  const float* ad2  = (const float*)d_in[14];
  const float* b2   = (const float*)d_in[15];
  const float* Wih0 = (const float*)d_in[16];
  const float* Whh0 = (const float*)d_in[17];
  const float* bih0 = (const float*)d_in[18];
  const float* bhh0 = (const float*)d_in[19];
  const float* Wih1 = (const float*)d_in[20];
  const float* Whh1 = (const float*)d_in[21];
  const float* bih1 = (const float*)d_in[22];
  const float* bhh1 = (const float*)d_in[23];
  const float* W2   = (const float*)d_in[24];
  const float* bn2g = (const float*)d_in[25];
  const float* bn2b = (const float*)d_in[26];
  const float* bn2m = (const float*)d_in[27];
  const float* bn2v = (const float*)d_in[28];
  const float* W3   = (const float*)d_in[29];
  const float* b3   = (const float*)d_in[30];

  char* ws = (char*)d_ws;
  u16*   xbf  = (u16*)(ws + O_XBF);
  u16*   x2b  = (u16*)(ws + O_XBF);
  u16*   w0t  = (u16*)(ws + O_W0T);
  u16*   wgt  = (u16*)(ws + O_WGT);
  u16*   w2t  = (u16*)(ws + O_W2T);
  u16*   xb   = (u16*)(ws + O_XB);
  u16*   hb   = (u16*)(ws + O_H);
  u64*   adjm = (u64*)(ws + O_ADJ);
  float* sc0  = (float*)(ws + O_SC0);
  float* sh0  = (float*)(ws + O_SH0);
  float* sc2  = (float*)(ws + O_SC2);
  float* sh2  = (float*)(ws + O_SH2);
  float* lb0  = (float*)(ws + O_LB0);
  float* lb1  = (float*)(ws + O_LB1);
  char*  s2sb = ws + O_H;
  u16*   ac0  = (u16*)(s2sb + S_AC0);
  u16*   ac1  = (u16*)(s2sb + S_AC1);
  float* c0b  = (float*)(s2sb + S_C0);
  float* c1b  = (float*)(s2sb + S_C1);
  float* h1f  = (float*)(s2sb + S_H1F);
  float* zp   = (float*)(s2sb + S_ZP);
  float* ebuf = (float*)(s2sb + S_E);
  float* z1u  = (float*)(s2sb + S_Z1U);

  setup_all<<<16432, 256, 0, stream>>>(x, W0, Wg1, Wg2, W2,
                                       bn0g, bn0b, bn0m, bn0v, bn2g, bn2b, bn2m, bn2v,
                                       bih0, bhh0, bih1, bhh1, pos,
                                       xbf, w0t, wgt, w2t, sc0, sh0, sc2, sh2, lb0, lb1, adjm);

  gemm8p<<<dim3(32, 8), 512, 0, stream>>>(xbf, w0t, xb, sc0, sh0, 8192, 2048, 2048);
  gemm_bf16<<<dim3(64, 8), 256, 0, stream>>>(xb, wgt, hb, 8192, 1024, 2048);
  gat_attn2<<<dim3(128, 16), 256, 0, stream>>>(adjm, hb, as1, ad1, as2, ad2, b1, b2, x2b);

  s2s0_gemv<<<1024, 256, 0, stream>>>(Wih1, lb1, lb0, z1u);
  s2s_e<0><<<2048, 256, 0, stream>>>(x2b, nullptr, z1u, ebuf);
  s2s_r<0><<<dim3(128, 4), 256, 0, stream>>>(x2b, ebuf, ac0, lb0, z1u, ac1, c0b, c1b);

  gemm_skf<<<dim3(64, 8), 256, 0, stream>>>(ac0, Wih0, Whh0, zp, 4096, 3072, 2048, 1024, 384);
  lstm_gate0<<<512, 256, 0, stream>>>(zp, lb0, c0b, ac0, ac1, 8);
  gemm_skf<<<dim3(64, 8), 256, 0, stream>>>(ac1, Wih1, Whh1, zp, 4096, 2048, 1024, 1024, 256);
  lstm_gate1<<<512, 256, 0, stream>>>(zp, lb1, c1b, h1f, ac1, ac0, 8);
  s2s_e<1><<<2048, 256, 0, stream>>>(x2b, h1f, nullptr, ebuf);
  s2s_r<1><<<dim3(128, 4), 256, 0, stream>>>(x2b, ebuf, ac0, nullptr, nullptr, nullptr, nullptr, nullptr);

  gemm_sk<<<dim3(16, 8), 256, 0, stream>>>(ac0, w2t, zp, 1024, 3072, 2048, 256);
  lin3<<<128, 256, 0, stream>>>(zp, sc2, sh2, W3, b3, (float*)d_out);
}